// Round 1
// baseline (56.701 us; speedup 1.0000x reference)
//
#include <hip/hip_runtime.h>
#include <hip/hip_bf16.h>

// Problem constants
constexpr int Bn = 4096;   // batch
constexpr int Vn = 64;     // nodes
constexpr int Hn = 512;    // hidden

typedef __attribute__((ext_vector_type(8))) short bf16x8;
typedef __attribute__((ext_vector_type(4))) float f32x4;
typedef __attribute__((ext_vector_type(8))) unsigned short u16x8;

__device__ __forceinline__ unsigned short f2bf(float f) {
    union { float f; unsigned int u; } x; x.f = f;
    unsigned int u = x.u;
    u += 0x7fffu + ((u >> 16) & 1u);   // round-to-nearest-even
    return (unsigned short)(u >> 16);
}

// ---------------------------------------------------------------------------
// Prep 1: W1w[v][k][n] = sigmoid(adjw[v][k]) * W1[v][k-(k>v)][n]  (0 if k==v)
// stored in mfma_f32_16x16x32_bf16 B-fragment layout:
//   flat = (((v*32 + nt)*2 + ks)*64 + lane)*8 + e
//   where n = nt*16 + (lane&15), k = ks*32 + (lane>>4)*8 + e
// One thread per (v, nt, ks, lane): writes its lane's 16B chunk.
// ---------------------------------------------------------------------------
__global__ void prep_w1(const float* __restrict__ adjw,
                        const float* __restrict__ W1,
                        unsigned short* __restrict__ bfrag) {
    int tid  = blockIdx.x * blockDim.x + threadIdx.x;   // 262144 threads
    int lane = tid & 63;
    int ks   = (tid >> 6) & 1;
    int nt   = (tid >> 7) & 31;
    int v    = tid >> 12;

    int n     = nt * 16 + (lane & 15);
    int kbase = ks * 32 + ((lane >> 4) << 3);

    u16x8 o;
#pragma unroll
    for (int e = 0; e < 8; ++e) {
        int k = kbase + e;
        float val = 0.f;
        if (k != v) {
            float aw = adjw[v * Vn + k];
            float s  = 1.f / (1.f + __expf(-aw));
            int  j   = k - (k > v);
            val = s * W1[((size_t)(v * (Vn - 1) + j)) * Hn + n];
        }
        o[e] = f2bf(val);
    }
    *reinterpret_cast<u16x8*>(bfrag + (size_t)tid * 8) = o;
}

// ---------------------------------------------------------------------------
// Prep 2: x (B x V fp32) -> bf16 A-fragment layout:
//   flat = ((mt*2 + ks)*64 + lane)*8 + e
//   where b = mt*16 + (lane&15), k = ks*32 + (lane>>4)*8 + e
// ---------------------------------------------------------------------------
__global__ void prep_x(const float* __restrict__ x,
                       unsigned short* __restrict__ afrag) {
    int tid  = blockIdx.x * blockDim.x + threadIdx.x;   // 32768 threads
    int lane = tid & 63;
    int ks   = (tid >> 6) & 1;
    int mt   = tid >> 7;

    int b     = mt * 16 + (lane & 15);
    int kbase = ks * 32 + ((lane >> 4) << 3);

    u16x8 o;
#pragma unroll
    for (int e = 0; e < 8; ++e)
        o[e] = f2bf(x[(size_t)b * Vn + kbase + e]);
    *reinterpret_cast<u16x8*>(afrag + (size_t)tid * 8) = o;
}

// ---------------------------------------------------------------------------
// Main: per block (btile, v): 64 rows of out[:, v].
// 4 waves; wave w handles n in [w*128, w*128+128) (8 n-tiles of 16).
// Per n-tile: 4 m-tiles x 2 k-steps of mfma 16x16x32 bf16, then fused
// relu + *W2 reduction into per-row partials (fp32, no h materialized).
// ---------------------------------------------------------------------------
__global__ __launch_bounds__(256)
void main_k(const unsigned short* __restrict__ afrag,
            const unsigned short* __restrict__ bfrag,
            const float* __restrict__ b1, const float* __restrict__ W2,
            const float* __restrict__ b2, float* __restrict__ out) {
    int btile = blockIdx.x;          // 0..63 (64 rows each)
    int v     = blockIdx.y;          // 0..63
    int wid   = threadIdx.x >> 6;
    int lane  = threadIdx.x & 63;

    // A fragments: 4 m-tiles x 2 k-steps (shared by all waves; L2-hot)
    bf16x8 a[4][2];
#pragma unroll
    for (int m = 0; m < 4; ++m)
#pragma unroll
        for (int ks = 0; ks < 2; ++ks) {
            int mt = btile * 4 + m;
            a[m][ks] = *reinterpret_cast<const bf16x8*>(
                afrag + ((size_t)(mt * 2 + ks)) * 512 + lane * 8);
        }

    float partial[4][4] = {};

#pragma unroll
    for (int j = 0; j < 8; ++j) {
        int nt = wid * 8 + j;
        const bf16x8 bf0 = *reinterpret_cast<const bf16x8*>(
            bfrag + ((size_t)((v * 32 + nt) * 2 + 0)) * 512 + lane * 8);
        const bf16x8 bf1 = *reinterpret_cast<const bf16x8*>(
            bfrag + ((size_t)((v * 32 + nt) * 2 + 1)) * 512 + lane * 8);

        f32x4 acc[4];
#pragma unroll
        for (int m = 0; m < 4; ++m) {
            f32x4 c = {0.f, 0.f, 0.f, 0.f};
            c = __builtin_amdgcn_mfma_f32_16x16x32_bf16(a[m][0], bf0, c, 0, 0, 0);
            c = __builtin_amdgcn_mfma_f32_16x16x32_bf16(a[m][1], bf1, c, 0, 0, 0);
            acc[m] = c;
        }

        int   n   = nt * 16 + (lane & 15);
        float w2v = W2[v * Hn + n];
        float b1v = b1[v * Hn + n];
#pragma unroll
        for (int m = 0; m < 4; ++m)
#pragma unroll
            for (int r = 0; r < 4; ++r) {
                float h = acc[m][r] + b1v;
                h = fmaxf(h, 0.f);
                partial[m][r] += h * w2v;
            }
    }

    // reduce over the 16-lane column group (bits 0..3 of lane)
#pragma unroll
    for (int m = 0; m < 4; ++m)
#pragma unroll
        for (int r = 0; r < 4; ++r) {
            float s = partial[m][r];
            s += __shfl_xor(s, 1);
            s += __shfl_xor(s, 2);
            s += __shfl_xor(s, 4);
            s += __shfl_xor(s, 8);
            partial[m][r] = s;
        }

    __shared__ float sdata[4][64];
    if ((lane & 15) == 0) {
        int hi = lane >> 4;
#pragma unroll
        for (int m = 0; m < 4; ++m)
#pragma unroll
            for (int r = 0; r < 4; ++r)
                sdata[wid][m * 16 + hi * 4 + r] = partial[m][r];
    }
    __syncthreads();

    if (threadIdx.x < 64) {
        int row = threadIdx.x;
        float s = sdata[0][row] + sdata[1][row] + sdata[2][row] + sdata[3][row]
                + b2[v];
        out[(size_t)(btile * 64 + row) * Vn + v] = s;
    }
}

extern "C" void kernel_launch(void* const* d_in, const int* in_sizes, int n_in,
                              void* d_out, int out_size, void* d_ws, size_t ws_size,
                              hipStream_t stream) {
    const float* x    = (const float*)d_in[0];
    const float* adjw = (const float*)d_in[1];
    const float* W1   = (const float*)d_in[2];
    const float* b1   = (const float*)d_in[3];
    const float* W2   = (const float*)d_in[4];
    const float* b2   = (const float*)d_in[5];
    float* out = (float*)d_out;

    // workspace: bfrag = 64*64*512 u16 (4 MiB), afrag = 4096*64 u16 (512 KiB)
    unsigned short* bfrag = (unsigned short*)d_ws;
    unsigned short* afrag = bfrag + (size_t)Vn * Vn * Hn;

    prep_w1<<<262144 / 256, 256, 0, stream>>>(adjw, W1, bfrag);
    prep_x<<<32768 / 256, 256, 0, stream>>>(x, afrag);
    main_k<<<dim3(64, 64), 256, 0, stream>>>(afrag, bfrag, b1, W2, b2, out);
}